// Round 1
// baseline (65.834 us; speedup 1.0000x reference)
//
#include <hip/hip_runtime.h>
#include <math.h>

// Problem constants (fixed by reference):
//   B=4, L=1024, C=128, D=64; rows = B*L = 4096
#define LL   1024
#define NROW 4096
#define DD   64
#define CC   128

// leaky(z) = C1*z + C2*|z|, C1=(1+s)/2, C2=(1-s)/2, s=0.01
#define C1H 0.505f
#define C2H 0.495f

static __device__ __forceinline__ void fma4(float4& a, float s, const float4 g) {
  a.x = fmaf(s, g.x, a.x); a.y = fmaf(s, g.y, a.y);
  a.z = fmaf(s, g.z, a.z); a.w = fmaf(s, g.w, a.w);
}

// ---------------------------------------------------------------------------
// k_proj: g_l = Q @ Wl, g_r = Q @ Wr  (per row, 64 outputs each)
//         AL[row] = dot(a, g_l[row]), AR[row] = dot(a, g_r[row])
// ---------------------------------------------------------------------------
__global__ __launch_bounds__(128) void k_proj(
    const float* __restrict__ q, const float* __restrict__ Wl,
    const float* __restrict__ Wr, const float* __restrict__ a,
    float* __restrict__ gl, float* __restrict__ gr,
    float* __restrict__ AL, float* __restrict__ AR) {
  int bl = blockIdx.x;          // 0..4095
  int t = threadIdx.x;          // 0..127
  __shared__ float qs[CC];
  qs[t] = q[bl * CC + t];
  __syncthreads();
  int d = t & 63;
  const float* __restrict__ W = (t < 64) ? Wl : Wr;
  float acc = 0.f;
#pragma unroll
  for (int c = 0; c < CC; ++c) acc = fmaf(qs[c], W[c * DD + d], acc);
  if (t < 64) gl[bl * DD + d] = acc; else gr[bl * DD + d] = acc;
  float v = a[d] * acc;
#pragma unroll
  for (int off = 32; off > 0; off >>= 1) v += __shfl_down(v, off, 64);
  if (d == 0) { if (t < 64) AL[bl] = v; else AR[bl] = v; }
}

// ---------------------------------------------------------------------------
// k_e: per block: 32 x-rows x 256-y range. Computes raw e into scores region
// of d_out + per-(row, yblock) online-softmax partials (m, s).
// LDS layout: rows of 16 float4 chunks, chunk index XOR-swizzled by (row>>2)&7
// so that the d-loop reads (8 distinct rows at the same chunk) hit 8 distinct
// bank groups (conflict-free, 8-lane broadcast each).
// ---------------------------------------------------------------------------
__global__ __launch_bounds__(256, 2) void k_e(
    const float* __restrict__ gl, const float* __restrict__ gr,
    const float* __restrict__ AL, const float* __restrict__ AR,
    const float* __restrict__ a,
    float* __restrict__ escore, float* __restrict__ m_part,
    float* __restrict__ s_part) {
  const int xt = blockIdx.x;           // 0..127
  const int yb = blockIdx.y;           // 0..3
  const int bl0 = xt * 32;             // global row base (doesn't straddle b)
  const int b = bl0 >> 10;
  const int y0 = yb * 256;
  const int t = threadIdx.x;
  const int tx = t & 7;                // x-group 0..7  (x = tx*4+i)
  const int ty = t >> 3;               // y-group 0..31 (y = ty*4+j)

  __shared__ float4 sGL[128 * 16];     // 32 KB, swizzled
  __shared__ float4 sGR[32 * 16];      // 8 KB, swizzled
  __shared__ float  sALs[128];
  __shared__ float  sM[4][8][4];
  __shared__ float  sS[4][8][4];

  // stage GR tile once (reused across all y-chunks)
  {
    const float4* g4 = (const float4*)(gr + bl0 * DD);
#pragma unroll
    for (int k = 0; k < 2; ++k) {
      int f = t * 2 + k;               // 0..511
      int x = f >> 4, c = f & 15;
      sGR[x * 16 + (c ^ (x >> 2))] = g4[f];
    }
  }

  float pr[4], m_run[4], s_run[4];
#pragma unroll
  for (int i = 0; i < 4; ++i) {
    pr[i] = C1H * AR[bl0 + tx * 4 + i];
    m_run[i] = -1e30f; s_run[i] = 0.f;
  }
  const float4* a4 = (const float4*)a;
  float4* esc4 = (float4*)escore;

  for (int yc = y0; yc < y0 + 256; yc += 128) {
    __syncthreads();
    {
      const float4* g4 = (const float4*)(gl + (b * LL + yc) * DD);
#pragma unroll
      for (int k = 0; k < 8; ++k) {
        int f = t + 256 * k;           // 0..2047, coalesced global read
        int y = f >> 4, c = f & 15;
        sGL[y * 16 + (c ^ ((y >> 2) & 7))] = g4[f];
      }
      if (t < 128) sALs[t] = AL[b * LL + yc + t];
    }
    __syncthreads();

    float accs[4][4];
#pragma unroll
    for (int i = 0; i < 4; ++i)
#pragma unroll
      for (int j = 0; j < 4; ++j) accs[i][j] = 0.f;

#pragma unroll
    for (int dq = 0; dq < 16; ++dq) {
      float4 aq = a4[dq];              // uniform -> scalar loads
      float4 glv[4], grv[4];
#pragma unroll
      for (int j = 0; j < 4; ++j)
        glv[j] = sGL[(ty * 4 + j) * 16 + (dq ^ (ty & 7))];
#pragma unroll
      for (int i = 0; i < 4; ++i)
        grv[i] = sGR[(tx * 4 + i) * 16 + (dq ^ tx)];
#pragma unroll
      for (int i = 0; i < 4; ++i)
#pragma unroll
        for (int j = 0; j < 4; ++j) {
          float s = accs[i][j];
          s = fmaf(fabsf(grv[i].x + glv[j].x), aq.x, s);
          s = fmaf(fabsf(grv[i].y + glv[j].y), aq.y, s);
          s = fmaf(fabsf(grv[i].z + glv[j].z), aq.z, s);
          s = fmaf(fabsf(grv[i].w + glv[j].w), aq.w, s);
          accs[i][j] = s;
        }
    }

    float4 alv = *(const float4*)&sALs[ty * 4];
    float pl0 = C1H * alv.x, pl1 = C1H * alv.y, pl2 = C1H * alv.z, pl3 = C1H * alv.w;
#pragma unroll
    for (int i = 0; i < 4; ++i) {
      float e0 = fmaf(C2H, accs[i][0], pr[i] + pl0);
      float e1 = fmaf(C2H, accs[i][1], pr[i] + pl1);
      float e2 = fmaf(C2H, accs[i][2], pr[i] + pl2);
      float e3 = fmaf(C2H, accs[i][3], pr[i] + pl3);
      float m4 = fmaxf(fmaxf(e0, e1), fmaxf(e2, e3));
      float mn = fmaxf(m_run[i], m4);
      float add = __expf(e0 - mn) + __expf(e1 - mn) +
                  __expf(e2 - mn) + __expf(e3 - mn);
      s_run[i] = fmaf(s_run[i], __expf(m_run[i] - mn), add);
      m_run[i] = mn;
      esc4[(bl0 + tx * 4 + i) * 256 + (yc >> 2) + ty] =
          make_float4(e0, e1, e2, e3);
    }
  }

  // reduce (m,s) across ty within wave (lanes differ in bits 3..5)
#pragma unroll
  for (int off = 8; off < 64; off <<= 1) {
#pragma unroll
    for (int i = 0; i < 4; ++i) {
      float mo = __shfl_xor(m_run[i], off, 64);
      float so = __shfl_xor(s_run[i], off, 64);
      float mn = fmaxf(m_run[i], mo);
      s_run[i] = s_run[i] * __expf(m_run[i] - mn) + so * __expf(mo - mn);
      m_run[i] = mn;
    }
  }
  int wv = t >> 6, lane = t & 63;
  if (lane < 8) {
#pragma unroll
    for (int i = 0; i < 4; ++i) { sM[wv][lane][i] = m_run[i]; sS[wv][lane][i] = s_run[i]; }
  }
  __syncthreads();
  if (t < 32) {                         // merge 4 waves, write partials
    int txx = t >> 2, ii = t & 3;
    float m = -1e30f, s = 0.f;
#pragma unroll
    for (int w = 0; w < 4; ++w) {
      float mo = sM[w][txx][ii], so = sS[w][txx][ii];
      float mn = fmaxf(m, mo);
      s = s * __expf(m - mn) + so * __expf(mo - mn);
      m = mn;
    }
    int r = bl0 + txx * 4 + ii;
    m_part[r * 4 + yb] = m;
    s_part[r * 4 + yb] = s;
  }
}

// ---------------------------------------------------------------------------
// k_merge: combine the 4 y-block partials per row -> final (m, 1/s)
// ---------------------------------------------------------------------------
__global__ __launch_bounds__(256) void k_merge(
    const float* __restrict__ m_part, const float* __restrict__ s_part,
    float* __restrict__ m_fin, float* __restrict__ is_fin) {
  int r = blockIdx.x * 256 + threadIdx.x;  // 0..4095
  float m = -1e30f, s = 0.f;
#pragma unroll
  for (int p = 0; p < 4; ++p) {
    float mo = m_part[r * 4 + p], so = s_part[r * 4 + p];
    float mn = fmaxf(m, mo);
    s = s * __expf(m - mn) + so * __expf(mo - mn);
    m = mn;
  }
  m_fin[r] = m;
  is_fin[r] = 1.0f / s;
}

// ---------------------------------------------------------------------------
// k_pv: per block: 16 x-rows. Re-read raw e, write normalized scores, and
// accumulate y = P @ g_r with (4x, 4d, 4y) register tiles, y split 4-way
// across thread groups, merged in LDS at the end.
// ---------------------------------------------------------------------------
__global__ __launch_bounds__(256) void k_pv(
    const float* __restrict__ grf, const float* __restrict__ m_fin,
    const float* __restrict__ is_fin, float* __restrict__ escore,
    float* __restrict__ yout) {
  const int blk = blockIdx.x;          // 0..255
  const int bl0 = blk * 16;
  const int b = bl0 >> 10;
  const int t = threadIdx.x;
  const int yg = t >> 6, l = t & 63, xq = l >> 4, dq = l & 15;

  __shared__ float4 sGR2[128 * 16];    // 32 KB, row-major (row-uniform reads)
  __shared__ float  sP[16][132];       // +4 pad breaks x-stride conflicts
  __shared__ float  sMF[16], sIS[16];
  __shared__ float4 sAcc[256 * 4];     // 16 KB

  if (t < 16) { sMF[t] = m_fin[bl0 + t]; sIS[t] = is_fin[bl0 + t]; }

  float4 acc[4];
#pragma unroll
  for (int i = 0; i < 4; ++i) acc[i] = make_float4(0.f, 0.f, 0.f, 0.f);

  float4* esc4 = (float4*)escore;
  __syncthreads();

  for (int yc = 0; yc < LL; yc += 128) {
    const float4* g4 = (const float4*)(grf + (b * LL + yc) * DD);
#pragma unroll
    for (int k = 0; k < 8; ++k) sGR2[t + 256 * k] = g4[t + 256 * k];
#pragma unroll
    for (int k = 0; k < 2; ++k) {
      int f = t + 256 * k;             // 0..511
      int x = f >> 5, cq = f & 31;
      int gi = (bl0 + x) * 256 + (yc >> 2) + cq;
      float4 e4 = esc4[gi];
      float mm = sMF[x], is = sIS[x];
      float4 p4 = make_float4(__expf(e4.x - mm) * is, __expf(e4.y - mm) * is,
                              __expf(e4.z - mm) * is, __expf(e4.w - mm) * is);
      esc4[gi] = p4;                   // final normalized scores
      *(float4*)&sP[x][cq * 4] = p4;
    }
    __syncthreads();
#pragma unroll
    for (int s = 0; s < 8; ++s) {
      int y4 = yg * 4 + s * 16;
      float4 g0 = sGR2[(y4 + 0) * 16 + dq];
      float4 g1 = sGR2[(y4 + 1) * 16 + dq];
      float4 g2 = sGR2[(y4 + 2) * 16 + dq];
      float4 g3 = sGR2[(y4 + 3) * 16 + dq];
#pragma unroll
      for (int i = 0; i < 4; ++i) {
        float4 p4 = *(const float4*)&sP[xq * 4 + i][y4];
        fma4(acc[i], p4.x, g0);
        fma4(acc[i], p4.y, g1);
        fma4(acc[i], p4.z, g2);
        fma4(acc[i], p4.w, g3);
      }
    }
    __syncthreads();
  }

#pragma unroll
  for (int i = 0; i < 4; ++i) sAcc[t * 4 + i] = acc[i];
  __syncthreads();
  if (t < 64) {
    float4* y4o = (float4*)yout;
#pragma unroll
    for (int i = 0; i < 4; ++i) {
      float4 r0 = sAcc[t * 4 + i];
      float4 r1 = sAcc[(t + 64) * 4 + i];
      float4 r2 = sAcc[(t + 128) * 4 + i];
      float4 r3 = sAcc[(t + 192) * 4 + i];
      r0.x += r1.x + r2.x + r3.x;
      r0.y += r1.y + r2.y + r3.y;
      r0.z += r1.z + r2.z + r3.z;
      r0.w += r1.w + r2.w + r3.w;
      int row = bl0 + xq * 4 + i;
      y4o[row * 16 + dq] = r0;
    }
  }
}

// ---------------------------------------------------------------------------
extern "C" void kernel_launch(void* const* d_in, const int* in_sizes, int n_in,
                              void* d_out, int out_size, void* d_ws, size_t ws_size,
                              hipStream_t stream) {
  const float* q  = (const float*)d_in[0];
  // d_in[1] = keys, d_in[2] = values: unused by the reference math
  const float* Wl = (const float*)d_in[3];
  const float* Wr = (const float*)d_in[4];
  const float* a  = (const float*)d_in[5];

  float* yout = (float*)d_out;                 // (4096, 64)
  float* esc  = yout + NROW * DD;              // (4096, 1024) scores region

  float* ws     = (float*)d_ws;                // ~2.3 MB total
  float* gl     = ws;                          // 4096*64
  float* gr     = gl + NROW * DD;              // 4096*64
  float* AL     = gr + NROW * DD;              // 4096
  float* AR     = AL + NROW;                   // 4096
  float* m_part = AR + NROW;                   // 4096*4
  float* s_part = m_part + NROW * 4;           // 4096*4
  float* m_fin  = s_part + NROW * 4;           // 4096
  float* is_fin = m_fin + NROW;                // 4096

  k_proj <<<NROW, 128, 0, stream>>>(q, Wl, Wr, a, gl, gr, AL, AR);
  k_e    <<<dim3(128, 4), 256, 0, stream>>>(gl, gr, AL, AR, a, esc, m_part, s_part);
  k_merge<<<16, 256, 0, stream>>>(m_part, s_part, m_fin, is_fin);
  k_pv   <<<256, 256, 0, stream>>>(gr, m_fin, is_fin, esc, yout);
}

// Round 2
// 65.726 us; speedup vs baseline: 1.0017x; 1.0017x over previous
//
#include <hip/hip_runtime.h>
#include <math.h>

// B=4, L=1024, C=128, D=64; rows = B*L = 4096
#define LL   1024
#define NROW 4096
#define DD   64
#define CC   128

// leaky(z) = C1*z + C2*|z|  (slope 0.01)
#define C1H 0.505f
#define C2H 0.495f

#define XR   8     // x-rows per fused block
#define YCH  128   // y-chunk length

static __device__ __forceinline__ void fma4(float4& a, float s, const float4 g) {
  a.x = fmaf(s, g.x, a.x); a.y = fmaf(s, g.y, a.y);
  a.z = fmaf(s, g.z, a.z); a.w = fmaf(s, g.w, a.w);
}

static __device__ __forceinline__ void accabs(float& s, const float4 r,
                                              const float4 l, const float4 aq) {
  s = fmaf(fabsf(r.x + l.x), aq.x, s);
  s = fmaf(fabsf(r.y + l.y), aq.y, s);
  s = fmaf(fabsf(r.z + l.z), aq.z, s);
  s = fmaf(fabsf(r.w + l.w), aq.w, s);
}

// ---------------------------------------------------------------------------
// k_proj: 4 rows/block, 256 threads. Each thread computes gl AND gr for one
// (row, d): 2 outputs, 256 fma, W loads L1-hot (64 consecutive d per wave).
// AL/AR = dot(a, g) via 64-lane shuffle reduce (wave == row group).
// ---------------------------------------------------------------------------
__global__ __launch_bounds__(256) void k_proj(
    const float* __restrict__ q, const float* __restrict__ Wl,
    const float* __restrict__ Wr, const float* __restrict__ a,
    float* __restrict__ gl, float* __restrict__ gr,
    float* __restrict__ AL, float* __restrict__ AR) {
  const int bl0 = blockIdx.x * 4;
  const int t = threadIdx.x;
  __shared__ float qs[4 * CC];
  qs[t] = q[bl0 * CC + t];
  qs[t + 256] = q[bl0 * CC + t + 256];
  __syncthreads();
  const int r = t >> 6, d = t & 63, row = bl0 + r;
  const float* qr = &qs[r * CC];
  float aL = 0.f, aR = 0.f;
#pragma unroll
  for (int c4 = 0; c4 < CC / 4; ++c4) {
    float4 qv = *(const float4*)&qr[c4 * 4];
    int cb = c4 * 4;
    aL = fmaf(qv.x, Wl[(cb + 0) * DD + d], aL);
    aR = fmaf(qv.x, Wr[(cb + 0) * DD + d], aR);
    aL = fmaf(qv.y, Wl[(cb + 1) * DD + d], aL);
    aR = fmaf(qv.y, Wr[(cb + 1) * DD + d], aR);
    aL = fmaf(qv.z, Wl[(cb + 2) * DD + d], aL);
    aR = fmaf(qv.z, Wr[(cb + 2) * DD + d], aR);
    aL = fmaf(qv.w, Wl[(cb + 3) * DD + d], aL);
    aR = fmaf(qv.w, Wr[(cb + 3) * DD + d], aR);
  }
  gl[row * DD + d] = aL;
  gr[row * DD + d] = aR;
  float av = a[d];
  float vL = av * aL, vR = av * aR;
#pragma unroll
  for (int off = 32; off > 0; off >>= 1) {
    vL += __shfl_down(vL, off, 64);
    vR += __shfl_down(vR, off, 64);
  }
  if (d == 0) { AL[row] = vL; AR[row] = vR; }
}

// ---------------------------------------------------------------------------
// k_fused: one block = 8 x-rows, 256 threads, 2 blocks/CU.
//   pass 1: e[8][1024] into LDS (gl staged in 128-y swizzled chunks)
//   softmax: in-block (32 threads/row), then normalize LDS in place and
//            write final scores to global ONCE
//   pass 2: PV from LDS P + swizzled gr chunks, 4x*4d register tiles
// ---------------------------------------------------------------------------
__global__ __launch_bounds__(256, 2) void k_fused(
    const float* __restrict__ gl, const float* __restrict__ gr,
    const float* __restrict__ AL, const float* __restrict__ AR,
    const float* __restrict__ a,
    float* __restrict__ scores, float* __restrict__ yout) {
  const int bl0 = blockIdx.x * XR;     // 512 blocks
  const int b = bl0 >> 10;
  const int t = threadIdx.x;

  __shared__ float  eT[XR][1028];      // 32,896 B (stride 1028 = 4 mod 32)
  __shared__ float4 gS[YCH * 16];      // 32 KB staging (gl pass1 / gr pass2 / acc)
  __shared__ float4 grOwn[XR * 16];    // 2 KB
  __shared__ float  sAv[DD];           // a in LDS (broadcast reads)
  __shared__ float  sAL[YCH];
  __shared__ float  sAR[XR];
  __shared__ float  sM[XR], sIS[XR];

  // ---- prolog staging ----
  if (t < XR * 16) {
    int x = t >> 4, c = t & 15;
    grOwn[x * 16 + (c ^ (x >> 2))] = ((const float4*)gr)[bl0 * 16 + t];
  }
  if (t >= 128 && t < 128 + DD) sAv[t - 128] = a[t - 128];
  if (t >= 192 && t < 192 + XR) sAR[t - 192] = AR[bl0 + (t - 192)];
  __syncthreads();

  // ---- pass 1: raw e into LDS ----
  const int tx = t & 3, ty = t >> 2;   // x-pair (2 rows), y-pair (2 cols)
  const float pr0 = C1H * sAR[tx * 2 + 0];
  const float pr1 = C1H * sAR[tx * 2 + 1];
  const int sw0 = (tx * 2 + 0) >> 2;   // grOwn swizzles
  const int sw1 = (tx * 2 + 1) >> 2;

  for (int yc = 0; yc < LL; yc += YCH) {
    __syncthreads();                   // protect gS reuse
    {
      const float4* g4 = (const float4*)(gl + ((size_t)b * LL + yc) * DD);
#pragma unroll
      for (int k = 0; k < 8; ++k) {
        int f = t + 256 * k;           // 0..2047
        int y = f >> 4, c = f & 15;
        gS[y * 16 + (c ^ ((y >> 2) & 15))] = g4[f];
      }
      if (t < YCH) sAL[t] = AL[b * LL + yc + t];
    }
    __syncthreads();

    float a00 = 0.f, a01 = 0.f, a10 = 0.f, a11 = 0.f;
    const int y0 = ty * 2 + 0, y1 = ty * 2 + 1;
    const int sy0 = (y0 >> 2) & 15, sy1 = (y1 >> 2) & 15;
#pragma unroll
    for (int dq = 0; dq < 16; ++dq) {
      float4 aq  = *(const float4*)&sAv[dq * 4];
      float4 gr0 = grOwn[(tx * 2 + 0) * 16 + (dq ^ sw0)];
      float4 gr1 = grOwn[(tx * 2 + 1) * 16 + (dq ^ sw1)];
      float4 gl0 = gS[y0 * 16 + (dq ^ sy0)];
      float4 gl1 = gS[y1 * 16 + (dq ^ sy1)];
      accabs(a00, gr0, gl0, aq);
      accabs(a01, gr0, gl1, aq);
      accabs(a10, gr1, gl0, aq);
      accabs(a11, gr1, gl1, aq);
    }
    const float pl0 = C1H * sAL[y0];
    const float pl1 = C1H * sAL[y1];
    float2 e0, e1;
    e0.x = fmaf(C2H, a00, pr0 + pl0);
    e0.y = fmaf(C2H, a01, pr0 + pl1);
    e1.x = fmaf(C2H, a10, pr1 + pl0);
    e1.y = fmaf(C2H, a11, pr1 + pl1);
    *(float2*)&eT[tx * 2 + 0][yc + ty * 2] = e0;
    *(float2*)&eT[tx * 2 + 1][yc + ty * 2] = e1;
  }
  __syncthreads();

  // ---- in-block softmax over each of the 8 rows ----
  {
    const int x = t >> 5, j = t & 31;  // 32 threads per row
    float m = -1e30f;
#pragma unroll
    for (int k = 0; k < 32; ++k) m = fmaxf(m, eT[x][k * 32 + j]);
#pragma unroll
    for (int off = 16; off > 0; off >>= 1) m = fmaxf(m, __shfl_xor(m, off, 64));
    float s = 0.f;
#pragma unroll
    for (int k = 0; k < 32; ++k) s += __expf(eT[x][k * 32 + j] - m);
#pragma unroll
    for (int off = 16; off > 0; off >>= 1) s += __shfl_xor(s, off, 64);
    if (j == 0) { sM[x] = m; sIS[x] = 1.0f / s; }
  }
  __syncthreads();

  // ---- normalize LDS in place + single coalesced scores write ----
  {
    float4* sc4 = (float4*)scores;
#pragma unroll
    for (int k = 0; k < 8; ++k) {
      int f = t + 256 * k;             // 0..2047
      int x = f >> 8, c = f & 255;
      float4 e4 = *(float4*)&eT[x][c * 4];
      float m = sM[x], is = sIS[x];
      float4 p;
      p.x = __expf(e4.x - m) * is;
      p.y = __expf(e4.y - m) * is;
      p.z = __expf(e4.z - m) * is;
      p.w = __expf(e4.w - m) * is;
      *(float4*)&eT[x][c * 4] = p;
      sc4[(size_t)(bl0 + x) * 256 + c] = p;
    }
  }

  // ---- pass 2: y = P @ gr, 4x*4d register tiles, y split 8-way ----
  const int dq = t & 15, xg = (t >> 4) & 1, yg = t >> 5;
  float4 acc0 = {0,0,0,0}, acc1 = {0,0,0,0}, acc2 = {0,0,0,0}, acc3 = {0,0,0,0};

  for (int yc = 0; yc < LL; yc += YCH) {
    __syncthreads();
    {
      const float4* g4 = (const float4*)(gr + ((size_t)b * LL + yc) * DD);
#pragma unroll
      for (int k = 0; k < 8; ++k) {
        int f = t + 256 * k;
        int y = f >> 4, c = f & 15;
        gS[y * 16 + (c ^ ((y >> 2) & 15))] = g4[f];
      }
    }
    __syncthreads();
#pragma unroll
    for (int yy4 = 0; yy4 < 4; ++yy4) {
      const int yb = yg * 16 + yy4 * 4;
      const int s0 = ((yb + 0) >> 2) & 15;   // same for yb..yb+3
      float4 p0 = *(float4*)&eT[xg * 4 + 0][yc + yb];
      float4 p1 = *(float4*)&eT[xg * 4 + 1][yc + yb];
      float4 p2 = *(float4*)&eT[xg * 4 + 2][yc + yb];
      float4 p3 = *(float4*)&eT[xg * 4 + 3][yc + yb];
      float4 g0 = gS[(yb + 0) * 16 + (dq ^ s0)];
      float4 g1 = gS[(yb + 1) * 16 + (dq ^ s0)];
      float4 g2 = gS[(yb + 2) * 16 + (dq ^ s0)];
      float4 g3 = gS[(yb + 3) * 16 + (dq ^ s0)];
      fma4(acc0, p0.x, g0); fma4(acc0, p0.y, g1); fma4(acc0, p0.z, g2); fma4(acc0, p0.w, g3);
      fma4(acc1, p1.x, g0); fma4(acc1, p1.y, g1); fma4(acc1, p1.z, g2); fma4(acc1, p1.w, g3);
      fma4(acc2, p2.x, g0); fma4(acc2, p2.y, g1); fma4(acc2, p2.z, g2); fma4(acc2, p2.w, g3);
      fma4(acc3, p3.x, g0); fma4(acc3, p3.y, g1); fma4(acc3, p3.z, g2); fma4(acc3, p3.w, g3);
    }
  }
  __syncthreads();

  // ---- reduce the 8 y-splits via LDS (reuse gS) and write y ----
  float4* sAcc = gS;
  sAcc[yg * 128 + (xg * 4 + 0) * 16 + dq] = acc0;
  sAcc[yg * 128 + (xg * 4 + 1) * 16 + dq] = acc1;
  sAcc[yg * 128 + (xg * 4 + 2) * 16 + dq] = acc2;
  sAcc[yg * 128 + (xg * 4 + 3) * 16 + dq] = acc3;
  __syncthreads();
  if (t < 128) {
    const int x = t >> 4, d4 = t & 15;
    float4 r = sAcc[x * 16 + d4];
#pragma unroll
    for (int w = 1; w < 8; ++w) {
      float4 o = sAcc[w * 128 + x * 16 + d4];
      r.x += o.x; r.y += o.y; r.z += o.z; r.w += o.w;
    }
    *(float4*)&yout[(size_t)(bl0 + x) * DD + d4 * 4] = r;
  }
}

// ---------------------------------------------------------------------------
extern "C" void kernel_launch(void* const* d_in, const int* in_sizes, int n_in,
                              void* d_out, int out_size, void* d_ws, size_t ws_size,
                              hipStream_t stream) {
  const float* q  = (const float*)d_in[0];
  // d_in[1] = keys, d_in[2] = values: unused by the reference math
  const float* Wl = (const float*)d_in[3];
  const float* Wr = (const float*)d_in[4];
  const float* a  = (const float*)d_in[5];

  float* yout = (float*)d_out;                 // (4096, 64)
  float* esc  = yout + NROW * DD;              // (4096, 1024) scores

  float* ws = (float*)d_ws;
  float* gl = ws;                              // 4096*64
  float* gr = gl + NROW * DD;                  // 4096*64
  float* AL = gr + NROW * DD;                  // 4096
  float* AR = AL + NROW;                       // 4096

  k_proj <<<NROW / 4, 256, 0, stream>>>(q, Wl, Wr, a, gl, gr, AL, AR);
  k_fused<<<NROW / XR, 256, 0, stream>>>(gl, gr, AL, AR, a, esc, yout);
}

// Round 3
// 54.238 us; speedup vs baseline: 1.2138x; 1.2118x over previous
//
#include <hip/hip_runtime.h>
#include <math.h>

// B=4, L=1024, C=128, D=64; rows = B*L = 4096
#define LL   1024
#define NROW 4096
#define DD   64
#define CC   128

// leaky(z) = C1*z + C2*|z|  (slope 0.01)
#define C1H 0.505f
#define C2H 0.495f

typedef short  bf16x8 __attribute__((ext_vector_type(8)));
typedef float  f32x4  __attribute__((ext_vector_type(4)));

static __device__ __forceinline__ unsigned short bf16rne(float f) {
  unsigned u = __float_as_uint(f);
  u += 0x7fffu + ((u >> 16) & 1u);
  return (unsigned short)(u >> 16);
}

static __device__ __forceinline__ void unpk(unsigned u, float& lo, float& hi) {
  lo = __uint_as_float(u << 16);
  hi = __uint_as_float(u & 0xffff0000u);
}

// ---------------------------------------------------------------------------
// k_proj: 8 rows/block, 256 threads; thread = (row-pair, d).
// Outputs: gl_bf (bf16), gr (fp32), grT_bf (bf16, [b][d][y] for MFMA B-frags),
//          AL/AR (fp32 row dots with a).
// 8 independent FMA chains -> no dep stalls.
// ---------------------------------------------------------------------------
__global__ __launch_bounds__(256) void k_proj(
    const float* __restrict__ q, const float* __restrict__ Wl,
    const float* __restrict__ Wr, const float* __restrict__ a,
    unsigned short* __restrict__ gl_bf, float* __restrict__ gr,
    unsigned short* __restrict__ grT_bf,
    float* __restrict__ AL, float* __restrict__ AR) {
  const int bl0 = blockIdx.x * 8;        // 512 blocks, no batch straddle
  const int b = bl0 >> 10;
  const int t = threadIdx.x;
  __shared__ __align__(16) float qs[8 * CC];          // 4 KB
  __shared__ __align__(16) unsigned short trT[DD][8]; // 1 KB

  ((float4*)qs)[t] = ((const float4*)(q + (size_t)bl0 * CC))[t];
  __syncthreads();

  const int rr = t >> 6;                 // 0..3 -> rows rr*2, rr*2+1
  const int d  = t & 63;
  const int r0 = rr * 2, r1 = rr * 2 + 1;
  const float* q0 = qs + r0 * CC;
  const float* q1 = qs + r1 * CC;

  float aL0 = 0, aL1 = 0, aR0 = 0, aR1 = 0;
  float bL0 = 0, bL1 = 0, bR0 = 0, bR1 = 0;
#pragma unroll 8
  for (int c = 0; c < CC; c += 2) {
    float wl0 = Wl[c * DD + d],       wr0 = Wr[c * DD + d];
    float wl1 = Wl[(c + 1) * DD + d], wr1 = Wr[(c + 1) * DD + d];
    aL0 = fmaf(q0[c], wl0, aL0);  bL0 = fmaf(q0[c + 1], wl1, bL0);
    aL1 = fmaf(q1[c], wl0, aL1);  bL1 = fmaf(q1[c + 1], wl1, bL1);
    aR0 = fmaf(q0[c], wr0, aR0);  bR0 = fmaf(q0[c + 1], wr1, bR0);
    aR1 = fmaf(q1[c], wr0, aR1);  bR1 = fmaf(q1[c + 1], wr1, bR1);
  }
  float gL0 = aL0 + bL0, gL1 = aL1 + bL1;
  float gR0 = aR0 + bR0, gR1 = aR1 + bR1;

  gl_bf[(size_t)(bl0 + r0) * DD + d] = bf16rne(gL0);
  gl_bf[(size_t)(bl0 + r1) * DD + d] = bf16rne(gL1);
  gr[(size_t)(bl0 + r0) * DD + d] = gR0;
  gr[(size_t)(bl0 + r1) * DD + d] = gR1;
  trT[d][r0] = bf16rne(gR0);
  trT[d][r1] = bf16rne(gR1);

  float av = a[d];
  float vL0 = av * gL0, vL1 = av * gL1, vR0 = av * gR0, vR1 = av * gR1;
#pragma unroll
  for (int off = 1; off < 64; off <<= 1) {
    vL0 += __shfl_xor(vL0, off, 64);
    vL1 += __shfl_xor(vL1, off, 64);
    vR0 += __shfl_xor(vR0, off, 64);
    vR1 += __shfl_xor(vR1, off, 64);
  }
  if (d == 0) {
    AL[bl0 + r0] = vL0; AL[bl0 + r1] = vL1;
    AR[bl0 + r0] = vR0; AR[bl0 + r1] = vR1;
  }
  __syncthreads();
  if (t < 64) {
    // grT_bf[b][d=t][y = bl0..bl0+7] : 8 bf16 = 16 B
    *(uint4*)&grT_bf[(((size_t)(b * 64 + t)) << 10) + (bl0 & 1023)] =
        *(const uint4*)&trT[t][0];
  }
}

// ---------------------------------------------------------------------------
// k_fused: block = 4 x-rows, 256 threads, grid 1024, 4 blocks/CU.
//  pass 1 (lane-owns-y): e[4x][4y] in regs; gl bf16 LDS chunks (swizzled),
//                        gr fp32 broadcast reads.
//  softmax: exact 2-phase (shuffle + tiny LDS reduce).
//  P: written to scores (fp32) + frag-major bf16 LDS tile for MFMA.
//  pass 2: PV via mfma_f32_16x16x32_bf16; B-frags straight from grT_bf (L2).
// ---------------------------------------------------------------------------
__global__ __launch_bounds__(256, 4) void k_fused(
    const unsigned short* __restrict__ gl_bf, const float* __restrict__ gr,
    const unsigned short* __restrict__ grT_bf,
    const float* __restrict__ AL, const float* __restrict__ AR,
    const float* __restrict__ a,
    float* __restrict__ scores, float* __restrict__ yout) {
  const int bl0 = blockIdx.x * 4;        // 1024 blocks
  const int b = bl0 >> 10;
  const int t = threadIdx.x;
  const int w = t >> 6, l = t & 63;

  // 32 KB region: gl chunk (pass 1)  ||  P frag-major bf16 (pass 2)
  __shared__ __align__(16) unsigned char lds_u[32768];
  __shared__ __align__(16) float grOwn[4 * DD];       // 1 KB, [x][d]
  __shared__ float sRedM[4][4], sRedS[4][4];
  __shared__ float sPV[4][4][16][4];                  // 4 KB [wave][nt][col][row]

  if (t < 64) ((float4*)grOwn)[t] = ((const float4*)(gr + (size_t)bl0 * DD))[t];

  float pr[4];
#pragma unroll
  for (int x = 0; x < 4; ++x) pr[x] = C1H * AR[bl0 + x];

  const float4* grOwn4 = (const float4*)grOwn;
  uint4* chunk = (uint4*)lds_u;
  float ev[4][4];                        // [x][yc]

#pragma unroll
  for (int yc = 0; yc < 4; ++yc) {
    __syncthreads();
    {
      const uint4* src = (const uint4*)gl_bf + ((size_t)(b * LL + yc * 256) * 8);
#pragma unroll
      for (int k = 0; k < 8; ++k) {
        int f = t + 256 * k;             // 0..2047 (coalesced)
        int y = f >> 3, g = f & 7;
        chunk[y * 8 + (g ^ (y & 7))] = src[f];
      }
    }
    float alv = AL[b * LL + yc * 256 + t];   // this lane's y
    __syncthreads();

    float pacc[4] = {0.f, 0.f, 0.f, 0.f};
#pragma unroll
    for (int dblk = 0; dblk < 4; ++dblk) {
      uint4 ga = chunk[t * 8 + ((dblk * 2 + 0) ^ (t & 7))];
      uint4 gb = chunk[t * 8 + ((dblk * 2 + 1) ^ (t & 7))];
      float glv[16];
      unpk(ga.x, glv[0], glv[1]);   unpk(ga.y, glv[2], glv[3]);
      unpk(ga.z, glv[4], glv[5]);   unpk(ga.w, glv[6], glv[7]);
      unpk(gb.x, glv[8], glv[9]);   unpk(gb.y, glv[10], glv[11]);
      unpk(gb.z, glv[12], glv[13]); unpk(gb.w, glv[14], glv[15]);
#pragma unroll
      for (int x = 0; x < 4; ++x) {
        float s = pacc[x];
#pragma unroll
        for (int c = 0; c < 4; ++c) {
          float4 gv = grOwn4[x * 16 + dblk * 4 + c];
          s = fmaf(fabsf(glv[c * 4 + 0] + gv.x), a[dblk * 16 + c * 4 + 0], s);
          s = fmaf(fabsf(glv[c * 4 + 1] + gv.y), a[dblk * 16 + c * 4 + 1], s);
          s = fmaf(fabsf(glv[c * 4 + 2] + gv.z), a[dblk * 16 + c * 4 + 2], s);
          s = fmaf(fabsf(glv[c * 4 + 3] + gv.w), a[dblk * 16 + c * 4 + 3], s);
        }
        pacc[x] = s;
      }
    }
    float pl = C1H * alv;
#pragma unroll
    for (int x = 0; x < 4; ++x) ev[x][yc] = fmaf(C2H, pacc[x], pr[x] + pl);
  }

  // ---- exact softmax: max phase ----
  float lm[4];
#pragma unroll
  for (int x = 0; x < 4; ++x)
    lm[x] = fmaxf(fmaxf(ev[x][0], ev[x][1]), fmaxf(ev[x][2], ev[x][3]));
#pragma unroll
  for (int off = 1; off < 64; off <<= 1) {
#pragma unroll
    for (int x = 0; x < 4; ++x) lm[x] = fmaxf(lm[x], __shfl_xor(lm[x], off, 64));
  }
  if (l == 0) {
#pragma unroll
    for (int x = 0; x < 4; ++x) sRedM[w][x] = lm[x];
  }
  __syncthreads();   // gl-chunk reads done everywhere; sRedM visible

  // zero the P frag tile (entire 32 KB region)
  {
    uint4 z = {0u, 0u, 0u, 0u};
#pragma unroll
    for (int k = 0; k < 8; ++k) chunk[t + 256 * k] = z;
  }
  float mfin[4], lsum[4];
#pragma unroll
  for (int x = 0; x < 4; ++x)
    mfin[x] = fmaxf(fmaxf(sRedM[0][x], sRedM[1][x]),
                    fmaxf(sRedM[2][x], sRedM[3][x]));
#pragma unroll
  for (int x = 0; x < 4; ++x) {
    lsum[x] = 0.f;
#pragma unroll
    for (int yc = 0; yc < 4; ++yc) {
      ev[x][yc] = __expf(ev[x][yc] - mfin[x]);
      lsum[x] += ev[x][yc];
    }
  }
#pragma unroll
  for (int off = 1; off < 64; off <<= 1) {
#pragma unroll
    for (int x = 0; x < 4; ++x) lsum[x] += __shfl_xor(lsum[x], off, 64);
  }
  if (l == 0) {
#pragma unroll
    for (int x = 0; x < 4; ++x) sRedS[w][x] = lsum[x];
  }
  __syncthreads();   // zeros done everywhere; sRedS visible

  float isv[4];
#pragma unroll
  for (int x = 0; x < 4; ++x)
    isv[x] = 1.0f / (sRedS[0][x] + sRedS[1][x] + sRedS[2][x] + sRedS[3][x]);

  // ---- P writes: scores (fp32, coalesced) + frag-major bf16 LDS ----
  unsigned short* eb = (unsigned short*)lds_u;
#pragma unroll
  for (int yc = 0; yc < 4; ++yc) {
    int y = yc * 256 + t;
    int kc = y >> 5, h = (y >> 3) & 3, j = y & 7;
#pragma unroll
    for (int x = 0; x < 4; ++x) {
      float p = ev[x][yc] * isv[x];
      scores[((size_t)(bl0 + x) << 10) + y] = p;
      eb[kc * 512 + (4 * x + h) * 8 + j] = bf16rne(p);  // granule 4x+h
    }
  }
  __syncthreads();

  // ---- pass 2: PV via MFMA, k-chunks split across waves ----
  f32x4 acc[4] = {{0.f, 0.f, 0.f, 0.f}, {0.f, 0.f, 0.f, 0.f},
                  {0.f, 0.f, 0.f, 0.f}, {0.f, 0.f, 0.f, 0.f}};
  const int row16 = l & 15, hh = l >> 4;
  const size_t bnBase = ((size_t)b * 64) << 10;
#pragma unroll
  for (int kk = 0; kk < 8; ++kk) {
    int kc = w + kk * 4;
    bf16x8 af = *(const bf16x8*)(lds_u + kc * 1024 + (4 * row16 + hh) * 16);
#pragma unroll
    for (int nt = 0; nt < 4; ++nt) {
      bf16x8 bfv = *(const bf16x8*)(grT_bf + bnBase +
                     (((size_t)(nt * 16 + row16)) << 10) + kc * 32 + hh * 8);
      acc[nt] = __builtin_amdgcn_mfma_f32_16x16x32_bf16(af, bfv, acc[nt], 0, 0, 0);
    }
  }
  if (l < 16) {
#pragma unroll
    for (int nt = 0; nt < 4; ++nt)
#pragma unroll
      for (int i = 0; i < 4; ++i) sPV[w][nt][l][i] = acc[nt][i];
  }
  __syncthreads();
  if (t < 64) {
    int nt = t >> 4, col = t & 15;
#pragma unroll
    for (int i = 0; i < 4; ++i) {
      float r = sPV[0][nt][col][i] + sPV[1][nt][col][i] +
                sPV[2][nt][col][i] + sPV[3][nt][col][i];
      yout[(size_t)(bl0 + i) * DD + nt * 16 + col] = r;
    }
  }
}

// ---------------------------------------------------------------------------
extern "C" void kernel_launch(void* const* d_in, const int* in_sizes, int n_in,
                              void* d_out, int out_size, void* d_ws, size_t ws_size,
                              hipStream_t stream) {
  const float* q  = (const float*)d_in[0];
  // d_in[1] = keys, d_in[2] = values: unused by the reference math
  const float* Wl = (const float*)d_in[3];
  const float* Wr = (const float*)d_in[4];
  const float* a  = (const float*)d_in[5];

  float* yout = (float*)d_out;                 // (4096, 64)
  float* esc  = yout + NROW * DD;              // (4096, 1024) scores

  // workspace layout (fp32 first, then bf16)
  float* ws = (float*)d_ws;
  float* gr = ws;                               // 4096*64 f32   (1 MB)
  float* AL = gr + NROW * DD;                   // 4096
  float* AR = AL + NROW;                        // 4096
  unsigned short* gl_bf  = (unsigned short*)(AR + NROW);          // 512 KB
  unsigned short* grT_bf = gl_bf + (size_t)NROW * DD;             // 512 KB

  k_proj <<<NROW / 8, 256, 0, stream>>>(q, Wl, Wr, a, gl_bf, gr, grT_bf, AL, AR);
  k_fused<<<NROW / 4, 256, 0, stream>>>(gl_bf, gr, grT_bf, AL, AR, a, esc, yout);
}

// Round 4
// 41.845 us; speedup vs baseline: 1.5733x; 1.2962x over previous
//
#include <hip/hip_runtime.h>
#include <math.h>

// B=4, L=1024, C=128, D=64; rows = B*L = 4096
#define LL   1024
#define NROW 4096
#define DD   64
#define CC   128

// leaky(z) = C1*z + C2*|z|  (slope 0.01)
#define C1H 0.505f
#define C2H 0.495f

typedef short  bf16x8 __attribute__((ext_vector_type(8)));
typedef float  f32x4  __attribute__((ext_vector_type(4)));

static __device__ __forceinline__ unsigned short bf16rne(float f) {
  unsigned u = __float_as_uint(f);
  u += 0x7fffu + ((u >> 16) & 1u);
  return (unsigned short)(u >> 16);
}

static __device__ __forceinline__ void unpk(unsigned u, float& lo, float& hi) {
  lo = __uint_as_float(u << 16);
  hi = __uint_as_float(u & 0xffff0000u);
}

// ---------------------------------------------------------------------------
// k_proj: 8 rows/block, 256 threads; thread = (row-pair, d).
// Outputs:
//   glg   : gl bf16, granule-major [b][g=d/8][y] as uint4 (8 bf16 = d 8g..8g+7)
//           -> k_fused lane-owns-y loads are perfectly coalesced dwordx4
//   gr    : fp32 row-major (k_fused reads it via uniform scalar loads)
//   grT_bf: bf16 [b][d][y] for MFMA B-frags
//   AL/AR : fp32 row dots with a
// ---------------------------------------------------------------------------
__global__ __launch_bounds__(256) void k_proj(
    const float* __restrict__ q, const float* __restrict__ Wl,
    const float* __restrict__ Wr, const float* __restrict__ a,
    uint4* __restrict__ glg, float* __restrict__ gr,
    unsigned short* __restrict__ grT_bf,
    float* __restrict__ AL, float* __restrict__ AR) {
  const int bl0 = blockIdx.x * 8;        // 512 blocks, no batch straddle
  const int b = bl0 >> 10;
  const int t = threadIdx.x;
  __shared__ __align__(16) float qs[8 * CC];          // 4 KB
  __shared__ __align__(16) unsigned short trT[DD][8]; // 1 KB
  __shared__ __align__(16) unsigned short trL[8][DD]; // 1 KB

  ((float4*)qs)[t] = ((const float4*)(q + (size_t)bl0 * CC))[t];
  __syncthreads();

  const int rr = t >> 6;                 // 0..3 -> rows rr*2, rr*2+1
  const int d  = t & 63;
  const int r0 = rr * 2, r1 = rr * 2 + 1;
  const float* q0 = qs + r0 * CC;
  const float* q1 = qs + r1 * CC;

  float aL0 = 0, aL1 = 0, aR0 = 0, aR1 = 0;
  float bL0 = 0, bL1 = 0, bR0 = 0, bR1 = 0;
#pragma unroll 8
  for (int c = 0; c < CC; c += 2) {
    float wl0 = Wl[c * DD + d],       wr0 = Wr[c * DD + d];
    float wl1 = Wl[(c + 1) * DD + d], wr1 = Wr[(c + 1) * DD + d];
    aL0 = fmaf(q0[c], wl0, aL0);  bL0 = fmaf(q0[c + 1], wl1, bL0);
    aL1 = fmaf(q1[c], wl0, aL1);  bL1 = fmaf(q1[c + 1], wl1, bL1);
    aR0 = fmaf(q0[c], wr0, aR0);  bR0 = fmaf(q0[c + 1], wr1, bR0);
    aR1 = fmaf(q1[c], wr0, aR1);  bR1 = fmaf(q1[c + 1], wr1, bR1);
  }
  float gL0 = aL0 + bL0, gL1 = aL1 + bL1;
  float gR0 = aR0 + bR0, gR1 = aR1 + bR1;

  trL[r0][d] = bf16rne(gL0);
  trL[r1][d] = bf16rne(gL1);
  gr[(size_t)(bl0 + r0) * DD + d] = gR0;
  gr[(size_t)(bl0 + r1) * DD + d] = gR1;
  trT[d][r0] = bf16rne(gR0);
  trT[d][r1] = bf16rne(gR1);

  float av = a[d];
  float vL0 = av * gL0, vL1 = av * gL1, vR0 = av * gR0, vR1 = av * gR1;
#pragma unroll
  for (int off = 1; off < 64; off <<= 1) {
    vL0 += __shfl_xor(vL0, off, 64);
    vL1 += __shfl_xor(vL1, off, 64);
    vR0 += __shfl_xor(vR0, off, 64);
    vR1 += __shfl_xor(vR1, off, 64);
  }
  if (d == 0) {
    AL[bl0 + r0] = vL0; AL[bl0 + r1] = vL1;
    AR[bl0 + r0] = vR0; AR[bl0 + r1] = vR1;
  }
  __syncthreads();
  if (t < 64) {
    // grT_bf[b][d=t][y = bl0..bl0+7] : 8 bf16 = 16 B
    *(uint4*)&grT_bf[(((size_t)(b * 64 + t)) << 10) + (bl0 & 1023)] =
        *(const uint4*)&trT[t][0];
  } else if (t < 128) {
    int tt = t - 64;
    int r = tt >> 3, g = tt & 7;       // row r, granule g (d = 8g..8g+7)
    glg[(((size_t)(b * 8 + g)) << 10) + (bl0 & 1023) + r] =
        *(const uint4*)&trL[r][g * 8];
  }
}

// ---------------------------------------------------------------------------
// k_fused: block = 4 x-rows, 256 threads, grid 1024, 5 blocks/CU.
//  pass 1 (lane-owns-y, NO LDS, NO barriers): gl from glg straight to VGPRs
//    (coalesced dwordx4, L2-hot); gr & a via block-uniform scalar loads.
//  softmax: exact 2-phase (shuffle + tiny LDS cross-wave reduce).
//  P: fp32 scores (coalesced) + packed bf16 frag tile in LDS (9 KB; MFMA
//    A-rows 4..15 read garbage -> D-rows 4..15 garbage, never read).
//  pass 2: PV via mfma_f32_16x16x32_bf16; B-frags from grT_bf (L2-hot).
// ---------------------------------------------------------------------------
__global__ __launch_bounds__(256, 5) void k_fused(
    const uint4* __restrict__ glg, const float* __restrict__ gr,
    const unsigned short* __restrict__ grT_bf,
    const float* __restrict__ AL, const float* __restrict__ AR,
    const float* __restrict__ a,
    float* __restrict__ scores, float* __restrict__ yout) {
  const int bl0 = blockIdx.x * 4;        // 1024 blocks
  const int b = bl0 >> 10;
  const int t = threadIdx.x;
  const int w = t >> 6, l = t & 63;

  __shared__ __align__(16) unsigned char pfrag[9216];  // packed P frags
  __shared__ float sRedM[4][4], sRedS[4][4];
  __shared__ __align__(16) float sPV[4][4][16][4];     // 4 KB

  // uniform loads -> scalar regs
  float pr[4];
#pragma unroll
  for (int x = 0; x < 4; ++x) pr[x] = C1H * AR[bl0 + x];

  float alv[4];
#pragma unroll
  for (int yc = 0; yc < 4; ++yc) alv[yc] = AL[b * LL + yc * 256 + t];

  // ---- pass 1: e in registers, dblk-outer ----
  float pacc[4][4];                      // [x][yc]
#pragma unroll
  for (int x = 0; x < 4; ++x)
#pragma unroll
    for (int yc = 0; yc < 4; ++yc) pacc[x][yc] = 0.f;

#pragma unroll
  for (int dblk = 0; dblk < 4; ++dblk) {
    uint4 gv[4][2];
#pragma unroll
    for (int yc = 0; yc < 4; ++yc)
#pragma unroll
      for (int g2 = 0; g2 < 2; ++g2)
        gv[yc][g2] = glg[(((size_t)(b * 8 + dblk * 2 + g2)) << 10) + yc * 256 + t];
#pragma unroll
    for (int yc = 0; yc < 4; ++yc) {
      float glv[16];
      unpk(gv[yc][0].x, glv[0], glv[1]);   unpk(gv[yc][0].y, glv[2], glv[3]);
      unpk(gv[yc][0].z, glv[4], glv[5]);   unpk(gv[yc][0].w, glv[6], glv[7]);
      unpk(gv[yc][1].x, glv[8], glv[9]);   unpk(gv[yc][1].y, glv[10], glv[11]);
      unpk(gv[yc][1].z, glv[12], glv[13]); unpk(gv[yc][1].w, glv[14], glv[15]);
#pragma unroll
      for (int x = 0; x < 4; ++x) {
        const float* __restrict__ grx = gr + (size_t)(bl0 + x) * DD + dblk * 16;
        const float* __restrict__ ax  = a + dblk * 16;
        float s = pacc[x][yc];
#pragma unroll
        for (int c = 0; c < 16; ++c)
          s = fmaf(fabsf(glv[c] + grx[c]), ax[c], s);
        pacc[x][yc] = s;
      }
    }
  }

  float ev[4][4];
#pragma unroll
  for (int x = 0; x < 4; ++x)
#pragma unroll
    for (int yc = 0; yc < 4; ++yc)
      ev[x][yc] = fmaf(C2H, pacc[x][yc], pr[x] + C1H * alv[yc]);

  // ---- exact softmax: max phase ----
  float lm[4];
#pragma unroll
  for (int x = 0; x < 4; ++x)
    lm[x] = fmaxf(fmaxf(ev[x][0], ev[x][1]), fmaxf(ev[x][2], ev[x][3]));
#pragma unroll
  for (int off = 1; off < 64; off <<= 1) {
#pragma unroll
    for (int x = 0; x < 4; ++x) lm[x] = fmaxf(lm[x], __shfl_xor(lm[x], off, 64));
  }
  if (l == 0) {
#pragma unroll
    for (int x = 0; x < 4; ++x) sRedM[w][x] = lm[x];
  }
  __syncthreads();                       // barrier 1

  float mfin[4], lsum[4];
#pragma unroll
  for (int x = 0; x < 4; ++x)
    mfin[x] = fmaxf(fmaxf(sRedM[0][x], sRedM[1][x]),
                    fmaxf(sRedM[2][x], sRedM[3][x]));
#pragma unroll
  for (int x = 0; x < 4; ++x) {
    lsum[x] = 0.f;
#pragma unroll
    for (int yc = 0; yc < 4; ++yc) {
      ev[x][yc] = __expf(ev[x][yc] - mfin[x]);
      lsum[x] += ev[x][yc];
    }
  }
#pragma unroll
  for (int off = 1; off < 64; off <<= 1) {
#pragma unroll
    for (int x = 0; x < 4; ++x) lsum[x] += __shfl_xor(lsum[x], off, 64);
  }
  if (l == 0) {
#pragma unroll
    for (int x = 0; x < 4; ++x) sRedS[w][x] = lsum[x];
  }
  __syncthreads();                       // barrier 2

  float isv[4];
#pragma unroll
  for (int x = 0; x < 4; ++x)
    isv[x] = 1.0f / (sRedS[0][x] + sRedS[1][x] + sRedS[2][x] + sRedS[3][x]);

  // ---- P writes: fp32 scores + packed bf16 frag tile ----
  unsigned short* eb = (unsigned short*)pfrag;
  const int hq = (t >> 3) & 3, jq = t & 7, kq = t >> 5;
#pragma unroll
  for (int yc = 0; yc < 4; ++yc) {
    int y = yc * 256 + t;
    int kc = yc * 8 + kq;                // y >> 5
#pragma unroll
    for (int x = 0; x < 4; ++x) {
      float p = ev[x][yc] * isv[x];
      scores[((size_t)(bl0 + x) << 10) + y] = p;
      eb[kc * 128 + (4 * x + hq) * 8 + jq] = bf16rne(p);
    }
  }
  __syncthreads();                       // barrier 3

  // ---- pass 2: PV via MFMA, kc split across waves ----
  f32x4 acc[4] = {{0.f, 0.f, 0.f, 0.f}, {0.f, 0.f, 0.f, 0.f},
                  {0.f, 0.f, 0.f, 0.f}, {0.f, 0.f, 0.f, 0.f}};
  const int row16 = l & 15, hh = l >> 4;
  const size_t bnBase = ((size_t)b * 64) << 10;
#pragma unroll
  for (int kk = 0; kk < 8; ++kk) {
    int kc = w + kk * 4;
    bf16x8 af = *(const bf16x8*)(pfrag + kc * 256 + (4 * row16 + hh) * 16);
#pragma unroll
    for (int nt = 0; nt < 4; ++nt) {
      bf16x8 bfv = *(const bf16x8*)(grT_bf + bnBase +
                     (((size_t)(nt * 16 + row16)) << 10) + kc * 32 + hh * 8);
      acc[nt] = __builtin_amdgcn_mfma_f32_16x16x32_bf16(af, bfv, acc[nt], 0, 0, 0);
    }
  }
  if (l < 16) {
#pragma unroll
    for (int nt = 0; nt < 4; ++nt)
#pragma unroll
      for (int i = 0; i < 4; ++i) sPV[w][nt][l][i] = acc[nt][i];
  }
  __syncthreads();                       // barrier 4
  if (t < 64) {
    int nt = t >> 4, col = t & 15;
#pragma unroll
    for (int i = 0; i < 4; ++i) {
      float r = sPV[0][nt][col][i] + sPV[1][nt][col][i] +
                sPV[2][nt][col][i] + sPV[3][nt][col][i];
      yout[(size_t)(bl0 + i) * DD + nt * 16 + col] = r;
    }
  }
}

// ---------------------------------------------------------------------------
extern "C" void kernel_launch(void* const* d_in, const int* in_sizes, int n_in,
                              void* d_out, int out_size, void* d_ws, size_t ws_size,
                              hipStream_t stream) {
  const float* q  = (const float*)d_in[0];
  // d_in[1] = keys, d_in[2] = values: unused by the reference math
  const float* Wl = (const float*)d_in[3];
  const float* Wr = (const float*)d_in[4];
  const float* a  = (const float*)d_in[5];

  float* yout = (float*)d_out;                 // (4096, 64)
  float* esc  = yout + NROW * DD;              // (4096, 1024) scores

  // workspace layout
  float* ws = (float*)d_ws;
  float* gr = ws;                               // 4096*64 f32  (1 MB)
  float* AL = gr + NROW * DD;                   // 4096
  float* AR = AL + NROW;                        // 4096
  uint4* glg = (uint4*)(AR + NROW);             // 4096*8 uint4 (512 KB), 16B-aligned
  unsigned short* grT_bf = (unsigned short*)(glg + (size_t)NROW * 8); // 512 KB

  k_proj <<<NROW / 8, 256, 0, stream>>>(q, Wl, Wr, a, glg, gr, grT_bf, AL, AR);
  k_fused<<<NROW / 4, 256, 0, stream>>>(glg, gr, grT_bf, AL, AR, a, esc, yout);
}

// Round 5
// 40.753 us; speedup vs baseline: 1.6154x; 1.0268x over previous
//
#include <hip/hip_runtime.h>
#include <math.h>

// B=4, L=1024, C=128, D=64; rows = B*L = 4096
#define LL   1024
#define NROW 4096
#define DD   64
#define CC   128

// leaky(z) = C1*z + C2*|z|  (slope 0.01)
#define C1H 0.505f
#define C2H 0.495f

typedef short  bf16x8 __attribute__((ext_vector_type(8)));
typedef float  f32x4  __attribute__((ext_vector_type(4)));

static __device__ __forceinline__ unsigned short bf16rne(float f) {
  unsigned u = __float_as_uint(f);
  u += 0x7fffu + ((u >> 16) & 1u);
  return (unsigned short)(u >> 16);
}

static __device__ __forceinline__ void unpk(unsigned u, float& lo, float& hi) {
  lo = __uint_as_float(u << 16);
  hi = __uint_as_float(u & 0xffff0000u);
}

// force a block-uniform float into an SGPR
static __device__ __forceinline__ float rflf(float v) {
  return __uint_as_float(__builtin_amdgcn_readfirstlane(__float_as_uint(v)));
}

// ---------------------------------------------------------------------------
// k_proj: 8 rows/block, 256 threads; thread = (row-pair, d).
// Outputs:
//   glg   : gl bf16, granule-major [b][g=d/8][y] as uint4 (8 bf16 = d 8g..8g+7)
//   gr    : fp32 row-major
//   grT_bf: bf16 [b][d][y] for MFMA B-frags
//   AL/AR : fp32 row dots with a
// ---------------------------------------------------------------------------
__global__ __launch_bounds__(256) void k_proj(
    const float* __restrict__ q, const float* __restrict__ Wl,
    const float* __restrict__ Wr, const float* __restrict__ a,
    uint4* __restrict__ glg, float* __restrict__ gr,
    unsigned short* __restrict__ grT_bf,
    float* __restrict__ AL, float* __restrict__ AR) {
  const int bl0 = blockIdx.x * 8;        // 512 blocks, no batch straddle
  const int b = bl0 >> 10;
  const int t = threadIdx.x;
  __shared__ __align__(16) float qs[8 * CC];          // 4 KB
  __shared__ __align__(16) unsigned short trT[DD][8]; // 1 KB
  __shared__ __align__(16) unsigned short trL[8][DD]; // 1 KB

  ((float4*)qs)[t] = ((const float4*)(q + (size_t)bl0 * CC))[t];
  __syncthreads();

  const int rr = t >> 6;                 // 0..3 -> rows rr*2, rr*2+1
  const int d  = t & 63;
  const int r0 = rr * 2, r1 = rr * 2 + 1;
  const float* q0 = qs + r0 * CC;
  const float* q1 = qs + r1 * CC;

  float aL0 = 0, aL1 = 0, aR0 = 0, aR1 = 0;
  float bL0 = 0, bL1 = 0, bR0 = 0, bR1 = 0;
#pragma unroll 8
  for (int c = 0; c < CC; c += 2) {
    float wl0 = Wl[c * DD + d],       wr0 = Wr[c * DD + d];
    float wl1 = Wl[(c + 1) * DD + d], wr1 = Wr[(c + 1) * DD + d];
    aL0 = fmaf(q0[c], wl0, aL0);  bL0 = fmaf(q0[c + 1], wl1, bL0);
    aL1 = fmaf(q1[c], wl0, aL1);  bL1 = fmaf(q1[c + 1], wl1, bL1);
    aR0 = fmaf(q0[c], wr0, aR0);  bR0 = fmaf(q0[c + 1], wr1, bR0);
    aR1 = fmaf(q1[c], wr0, aR1);  bR1 = fmaf(q1[c + 1], wr1, bR1);
  }
  float gL0 = aL0 + bL0, gL1 = aL1 + bL1;
  float gR0 = aR0 + bR0, gR1 = aR1 + bR1;

  trL[r0][d] = bf16rne(gL0);
  trL[r1][d] = bf16rne(gL1);
  gr[(size_t)(bl0 + r0) * DD + d] = gR0;
  gr[(size_t)(bl0 + r1) * DD + d] = gR1;
  trT[d][r0] = bf16rne(gR0);
  trT[d][r1] = bf16rne(gR1);

  float av = a[d];
  float vL0 = av * gL0, vL1 = av * gL1, vR0 = av * gR0, vR1 = av * gR1;
#pragma unroll
  for (int off = 1; off < 64; off <<= 1) {
    vL0 += __shfl_xor(vL0, off, 64);
    vL1 += __shfl_xor(vL1, off, 64);
    vR0 += __shfl_xor(vR0, off, 64);
    vR1 += __shfl_xor(vR1, off, 64);
  }
  if (d == 0) {
    AL[bl0 + r0] = vL0; AL[bl0 + r1] = vL1;
    AR[bl0 + r0] = vR0; AR[bl0 + r1] = vR1;
  }
  __syncthreads();
  if (t < 64) {
    *(uint4*)&grT_bf[(((size_t)(b * 64 + t)) << 10) + (bl0 & 1023)] =
        *(const uint4*)&trT[t][0];
  } else if (t < 128) {
    int tt = t - 64;
    int r = tt >> 3, g = tt & 7;       // row r, granule g (d = 8g..8g+7)
    glg[(((size_t)(b * 8 + g)) << 10) + (bl0 & 1023) + r] =
        *(const uint4*)&trL[r][g * 8];
  }
}

// ---------------------------------------------------------------------------
// k_fused: block = 4 x-rows, 256 threads, grid 1024, 4 blocks/CU.
//  pass 1 (lane-owns-y): gl from glg straight to VGPRs (coalesced, L2-hot);
//    gr & a snapshot into SGPRs via readfirstlane -> inner loop is pure VALU
//    (v_add v,v,s ; v_fma acc, abs(v), s, acc), zero VMEM/LDS inside.
//  softmax: exact 2-phase (shuffle + tiny LDS cross-wave reduce).
//  P: fp32 scores (nontemporal, coalesced) + packed bf16 frag tile in LDS.
//  pass 2: PV via mfma_f32_16x16x32_bf16; B-frags from grT_bf (L2-hot).
// ---------------------------------------------------------------------------
__global__ __launch_bounds__(256, 4) void k_fused(
    const uint4* __restrict__ glg, const float* __restrict__ gr,
    const unsigned short* __restrict__ grT_bf,
    const float* __restrict__ AL, const float* __restrict__ AR,
    const float* __restrict__ a,
    float* __restrict__ scores, float* __restrict__ yout) {
  const int bl0 = blockIdx.x * 4;        // 1024 blocks
  const int b = bl0 >> 10;
  const int t = threadIdx.x;
  const int w = t >> 6, l = t & 63;

  __shared__ __align__(16) unsigned char pfrag[9216];  // packed P frags
  __shared__ float sRedM[4][4], sRedS[4][4];
  __shared__ __align__(16) float sPV[4][4][16][4];     // 4 KB

  float pr[4];
#pragma unroll
  for (int x = 0; x < 4; ++x) pr[x] = C1H * rflf(AR[bl0 + x]);

  float alv[4];
#pragma unroll
  for (int yc = 0; yc < 4; ++yc) alv[yc] = AL[b * LL + yc * 256 + t];

  // ---- pass 1: e in registers, dblk-outer; gr/a in SGPRs ----
  float pacc[4][4];                      // [x][yc]
#pragma unroll
  for (int x = 0; x < 4; ++x)
#pragma unroll
    for (int yc = 0; yc < 4; ++yc) pacc[x][yc] = 0.f;

#pragma unroll
  for (int dblk = 0; dblk < 4; ++dblk) {
    // batched gl loads for this dblk (8 x uint4 = 32 VGPR, hoisted)
    uint4 gv[4][2];
#pragma unroll
    for (int yc = 0; yc < 4; ++yc)
#pragma unroll
      for (int g2 = 0; g2 < 2; ++g2)
        gv[yc][g2] = glg[(((size_t)(b * 8 + dblk * 2 + g2)) << 10) + yc * 256 + t];

    // snapshot a[dblk*16 .. +16) into 16 SGPRs
    float sa[16];
#pragma unroll
    for (int c4 = 0; c4 < 4; ++c4) {
      float4 v = *(const float4*)&a[dblk * 16 + c4 * 4];
      sa[c4 * 4 + 0] = rflf(v.x); sa[c4 * 4 + 1] = rflf(v.y);
      sa[c4 * 4 + 2] = rflf(v.z); sa[c4 * 4 + 3] = rflf(v.w);
    }
    // snapshot gr[x][dblk*16 .. +16) into 64 SGPRs
    float sgr[4][16];
#pragma unroll
    for (int x = 0; x < 4; ++x)
#pragma unroll
      for (int c4 = 0; c4 < 4; ++c4) {
        float4 v = *(const float4*)&gr[(size_t)(bl0 + x) * DD + dblk * 16 + c4 * 4];
        sgr[x][c4 * 4 + 0] = rflf(v.x); sgr[x][c4 * 4 + 1] = rflf(v.y);
        sgr[x][c4 * 4 + 2] = rflf(v.z); sgr[x][c4 * 4 + 3] = rflf(v.w);
      }

#pragma unroll
    for (int yc = 0; yc < 4; ++yc) {
      float glv[16];
      unpk(gv[yc][0].x, glv[0], glv[1]);   unpk(gv[yc][0].y, glv[2], glv[3]);
      unpk(gv[yc][0].z, glv[4], glv[5]);   unpk(gv[yc][0].w, glv[6], glv[7]);
      unpk(gv[yc][1].x, glv[8], glv[9]);   unpk(gv[yc][1].y, glv[10], glv[11]);
      unpk(gv[yc][1].z, glv[12], glv[13]); unpk(gv[yc][1].w, glv[14], glv[15]);
#pragma unroll
      for (int x = 0; x < 4; ++x) {
        float s = pacc[x][yc];
#pragma unroll
        for (int c = 0; c < 16; ++c)
          s = fmaf(fabsf(glv[c] + sgr[x][c]), sa[c], s);
        pacc[x][yc] = s;
      }
    }
  }

  float ev[4][4];
#pragma unroll
  for (int x = 0; x < 4; ++x)
#pragma unroll
    for (int yc = 0; yc < 4; ++yc)
      ev[x][yc] = fmaf(C2H, pacc[x][yc], pr[x] + C1H * alv[yc]);

  // ---- exact softmax: max phase ----
  float lm[4];
#pragma unroll
  for (int x = 0; x < 4; ++x)
    lm[x] = fmaxf(fmaxf(ev[x][0], ev[x][1]), fmaxf(ev[x][2], ev[x][3]));
#pragma unroll
  for (int off = 1; off < 64; off <<= 1) {
#pragma unroll
    for (int x = 0; x < 4; ++x) lm[x] = fmaxf(lm[x], __shfl_xor(lm[x], off, 64));
  }
  if (l == 0) {
#pragma unroll
    for (int x = 0; x < 4; ++x) sRedM[w][x] = lm[x];
  }
  __syncthreads();                       // barrier 1

  float mfin[4], lsum[4];
#pragma unroll
  for (int x = 0; x < 4; ++x)
    mfin[x] = fmaxf(fmaxf(sRedM[0][x], sRedM[1][x]),
                    fmaxf(sRedM[2][x], sRedM[3][x]));
#pragma unroll
  for (int x = 0; x < 4; ++x) {
    lsum[x] = 0.f;
#pragma unroll
    for (int yc = 0; yc < 4; ++yc) {
      ev[x][yc] = __expf(ev[x][yc] - mfin[x]);
      lsum[x] += ev[x][yc];
    }
  }
#pragma unroll
  for (int off = 1; off < 64; off <<= 1) {
#pragma unroll
    for (int x = 0; x < 4; ++x) lsum[x] += __shfl_xor(lsum[x], off, 64);
  }
  if (l == 0) {
#pragma unroll
    for (int x = 0; x < 4; ++x) sRedS[w][x] = lsum[x];
  }
  __syncthreads();                       // barrier 2

  float isv[4];
#pragma unroll
  for (int x = 0; x < 4; ++x)
    isv[x] = 1.0f / (sRedS[0][x] + sRedS[1][x] + sRedS[2][x] + sRedS[3][x]);

  // ---- P writes: fp32 scores (nontemporal) + packed bf16 frag tile ----
  unsigned short* eb = (unsigned short*)pfrag;
  const int hq = (t >> 3) & 3, jq = t & 7, kq = t >> 5;
#pragma unroll
  for (int yc = 0; yc < 4; ++yc) {
    int y = yc * 256 + t;
    int kc = yc * 8 + kq;                // y >> 5
#pragma unroll
    for (int x = 0; x < 4; ++x) {
      float p = ev[x][yc] * isv[x];
      __builtin_nontemporal_store(p, &scores[((size_t)(bl0 + x) << 10) + y]);
      eb[kc * 128 + (4 * x + hq) * 8 + jq] = bf16rne(p);
    }
  }
  __syncthreads();                       // barrier 3

  // ---- pass 2: PV via MFMA, kc split across waves ----
  f32x4 acc[4] = {{0.f, 0.f, 0.f, 0.f}, {0.f, 0.f, 0.f, 0.f},
                  {0.f, 0.f, 0.f, 0.f}, {0.f, 0.f, 0.f, 0.f}};
  const int row16 = l & 15, hh = l >> 4;
  const size_t bnBase = ((size_t)b * 64) << 10;
#pragma unroll
  for (int kk = 0; kk < 8; ++kk) {
    int kc = w + kk * 4;
    bf16x8 af = *(const bf16x8*)(pfrag + kc * 256 + (4 * row16 + hh) * 16);
#pragma unroll
    for (int nt = 0; nt < 4; ++nt) {
      bf16x8 bfv = *(const bf16x8*)(grT_bf + bnBase +
                     (((size_t)(nt * 16 + row16)) << 10) + kc * 32 + hh * 8);
      acc[nt] = __builtin_amdgcn_mfma_f32_16x16x32_bf16(af, bfv, acc[nt], 0, 0, 0);
    }
  }
  if (l < 16) {
#pragma unroll
    for (int nt = 0; nt < 4; ++nt)
#pragma unroll
      for (int i = 0; i < 4; ++i) sPV[w][nt][l][i] = acc[nt][i];
  }
  __syncthreads();                       // barrier 4
  if (t < 64) {
    int nt = t >> 4, col = t & 15;
#pragma unroll
    for (int i = 0; i < 4; ++i) {
      float r = sPV[0][nt][col][i] + sPV[1][nt][col][i] +
                sPV[2][nt][col][i] + sPV[3][nt][col][i];
      yout[(size_t)(bl0 + i) * DD + nt * 16 + col] = r;
    }
  }
}

// ---------------------------------------------------------------------------
extern "C" void kernel_launch(void* const* d_in, const int* in_sizes, int n_in,
                              void* d_out, int out_size, void* d_ws, size_t ws_size,
                              hipStream_t stream) {
  const float* q  = (const float*)d_in[0];
  // d_in[1] = keys, d_in[2] = values: unused by the reference math
  const float* Wl = (const float*)d_in[3];
  const float* Wr = (const float*)d_in[4];
  const float* a  = (const float*)d_in[5];

  float* yout = (float*)d_out;                 // (4096, 64)
  float* esc  = yout + NROW * DD;              // (4096, 1024) scores

  float* ws = (float*)d_ws;
  float* gr = ws;                               // 4096*64 f32  (1 MB)
  float* AL = gr + NROW * DD;                   // 4096
  float* AR = AL + NROW;                        // 4096
  uint4* glg = (uint4*)(AR + NROW);             // 4096*8 uint4 (512 KB)
  unsigned short* grT_bf = (unsigned short*)(glg + (size_t)NROW * 8); // 512 KB

  k_proj <<<NROW / 8, 256, 0, stream>>>(q, Wl, Wr, a, glg, gr, grT_bf, AL, AR);
  k_fused<<<NROW / 4, 256, 0, stream>>>(glg, gr, grT_bf, AL, AR, a, esc, yout);
}